// Round 5
// baseline (811.514 us; speedup 1.0000x reference)
//
#include <hip/hip_runtime.h>

// IrradianceVolumes: out[i,c] = relu( sum_j sh_j(normal_i) * trilerp(coeff[...,j,c], point_i) )
// coeff: [128,128,128,16,3] f32 (403 MB), points/normals: [2M,3] f32, out: [2M,3] f32.
//
// Round 9:
//  - The ~248us fillBufferAligned is the HARNESS's 1.6 GB workspace re-poison
//    (6.5 TB/s, every iteration, untouchable). Budget excl. poison: ~500us, split
//    ~250/~250 between scatter_data and main_data (neither made top-5, cutoff 246).
//  - main: persistent producer/consumer pipeline. grid=256 (1 block/CU), 512 thr,
//    double-buffered 5x9x9 halo (2 x 78,480 B = 156,960 B LDS). Waves 0-3 compute
//    bin k while waves 4-7 stage bin k+1 -> staging HBM overlaps LDS compute.
//    Block owns 32 consecutive bins -> halo overlap layers hit its own L2.
//  - scatter: REPL 4->16 (same-address atomic chain 61 -> ~15 hops) and slot
//    records padded to a PRIVATE 64-B line, written in full (no partial-line RMW,
//    no cross-XCD line sharing). Slots 335 MB (ws is 1.6 GB).
//  - keep: z-column +1-f4 pad LDS layout (bank fix, conflicts 6.2e7 -> 2.4e7),
//    capacity bins + overflow list + resweep flag, direct fallback.

constexpr int RES = 128;
constexpr int D2 = 16;
constexpr int CSTRIDE = D2 * 3;       // 48 floats per cell
constexpr int CELL_F4 = CSTRIDE / 4;  // 12 float4 per cell

// bins: x split by 4 (shift 2), y/z by 8 (shift 3)
constexpr int NBX = 32, NBY = 16, NBZ = 16;
constexpr int NBINS = NBX * NBY * NBZ;     // 8192
constexpr int HX = 5, HY = 9, HZ = 9;      // halo cells per axis

// LDS layout: [col = cx*HY+cy][z-column of 9 cells, padded +1 f4]
constexpr int SRC_COL_F4 = HZ * CELL_F4;        // 108 f4 real data per column
constexpr int COL_F4 = SRC_COL_F4 + 1;          // 109 -> start-group spread (5 coprime 8)
constexpr int NCOL = HX * HY;                   // 45 columns
constexpr int TOT_SRC_F4 = NCOL * SRC_COL_F4;   // 4860 f4 staged from HBM per bin
constexpr int LDS_F4 = NCOL * COL_F4;           // 4905 f4 = 78,480 B per buffer

constexpr int MAIN_THREADS = 512;               // 4 compute waves + 4 stage waves
constexpr int BINS_PER_BLOCK = 32;
constexpr int MAIN_GRID = NBINS / BINS_PER_BLOCK; // 256 = 1 block/CU

constexpr int REPL = 16;         // counter/segment replicas per bin (chain ~15/addr)
constexpr int CAP = 40;          // slots per (bin,replica); lambda=15.3 -> P(ovf)~1e-9
constexpr int CNT_PAD = 16;      // ints per padded counter (64 B line)
constexpr int OVF_CAP = 131072;  // overflow list capacity (512 KB)

__device__ __forceinline__ void grid_coords(const float* aabb, float px, float py, float pz,
                                            int& ix, int& iy, int& iz,
                                            float& fx, float& fy, float& fz)
{
    const float a0 = aabb[0], a1 = aabb[1], a2 = aabb[2];
    const float b0 = aabb[3], b1 = aabb[4], b2 = aabb[5];
    float gx = (px - a0) / (b0 - a0) * (float)(RES - 1);
    float gy = (py - a1) / (b1 - a1) * (float)(RES - 1);
    float gz = (pz - a2) / (b2 - a2) * (float)(RES - 1);
    gx = fminf(fmaxf(gx, 0.0f), (float)(RES - 1));
    gy = fminf(fmaxf(gy, 0.0f), (float)(RES - 1));
    gz = fminf(fmaxf(gz, 0.0f), (float)(RES - 1));
    ix = min((int)floorf(gx), RES - 2);
    iy = min((int)floorf(gy), RES - 2);
    iz = min((int)floorf(gz), RES - 2);
    fx = gx - (float)ix;
    fy = gy - (float)iy;
    fz = gz - (float)iz;
}

__device__ __forceinline__ int bin_of(int ix, int iy, int iz)
{
    return (((ix >> 2) * NBY) + (iy >> 3)) * NBZ + (iz >> 3);
}

__device__ __forceinline__ void sh_basis(float nx, float ny, float nz, float* sh)
{
    const float xx = nx * nx, yy = ny * ny, zz = nz * nz;
    const float xy = nx * ny, yz = ny * nz, xz = nx * nz;
    sh[0]  = 0.28209479177387814f;
    sh[1]  = -0.4886025119029199f * ny;
    sh[2]  = 0.4886025119029199f * nz;
    sh[3]  = -0.4886025119029199f * nx;
    sh[4]  = 1.0925484305920792f * xy;
    sh[5]  = -1.0925484305920792f * yz;
    sh[6]  = 0.31539156525252005f * (2.0f * zz - xx - yy);
    sh[7]  = -1.0925484305920792f * xz;
    sh[8]  = 0.5462742152960396f * (xx - yy);
    sh[9]  = -0.5900435899266435f * ny * (3.0f * xx - yy);
    sh[10] = 2.890611442640554f * xy * nz;
    sh[11] = -0.4570457994644658f * ny * (4.0f * zz - xx - yy);
    sh[12] = 0.3731763325901154f * nz * (2.0f * zz - 3.0f * xx - 3.0f * yy);
    sh[13] = -0.4570457994644658f * nx * (4.0f * zz - xx - yy);
    sh[14] = 1.445305721320277f * nz * (xx - yy);
    sh[15] = -0.5900435899266435f * nx * (xx - 3.0f * yy);
}

// Shared inner math: given point/normal + LDS halo buffer, accumulate and store.
__device__ __forceinline__ void eval_from_lds(
    const float4* __restrict__ lds4, const float* __restrict__ aabb,
    float px, float py, float pz, float nx, float ny, float nz,
    int x0, int y0, int z0, int i, float* __restrict__ out)
{
    int ix, iy, iz; float fx, fy, fz;
    grid_coords(aabb, px, py, pz, ix, iy, iz, fx, fy, fz);
    const int lx = ix - x0, ly = iy - y0, lz = iz - z0;

    float sh[D2];
    sh_basis(nx, ny, nz, sh);

    const float wz0 = 1.0f - fz, wz1 = fz;
    float acc0 = 0.0f, acc1 = 0.0f, acc2 = 0.0f;

#pragma unroll
    for (int dx = 0; dx < 2; ++dx) {
        const float wx = dx ? fx : 1.0f - fx;
#pragma unroll
        for (int dy = 0; dy < 2; ++dy) {
            const float wxy = wx * (dy ? fy : 1.0f - fy);
            // contiguous 24 f4 within one padded z-column (covers lz, lz+1)
            const int lbase = ((lx + dx) * HY + (ly + dy)) * COL_F4 + lz * CELL_F4;
            union { float4 q[24]; float v[96]; } u;
#pragma unroll
            for (int kk = 0; kk < 24; ++kk) u.q[kk] = lds4[lbase + kk];

            float s00 = 0.f, s01 = 0.f, s02 = 0.f;
            float s10 = 0.f, s11 = 0.f, s12 = 0.f;
#pragma unroll
            for (int j = 0; j < D2; ++j) {
                const float s = sh[j];
                s00 = fmaf(s, u.v[3 * j + 0], s00);
                s01 = fmaf(s, u.v[3 * j + 1], s01);
                s02 = fmaf(s, u.v[3 * j + 2], s02);
                s10 = fmaf(s, u.v[48 + 3 * j + 0], s10);
                s11 = fmaf(s, u.v[48 + 3 * j + 1], s11);
                s12 = fmaf(s, u.v[48 + 3 * j + 2], s12);
            }
            const float w0 = wxy * wz0, w1 = wxy * wz1;
            acc0 = fmaf(w0, s00, fmaf(w1, s10, acc0));
            acc1 = fmaf(w0, s01, fmaf(w1, s11, acc1));
            acc2 = fmaf(w0, s02, fmaf(w1, s12, acc2));
        }
    }

    out[3 * i + 0] = fmaxf(acc0, 0.0f);
    out[3 * i + 1] = fmaxf(acc1, 0.0f);
    out[3 * i + 2] = fmaxf(acc2, 0.0f);
}

// Fully-direct per-point evaluation from global memory (fallback / overflow path).
__device__ void compute_point_global(
    const float* __restrict__ coeff,
    const float* __restrict__ aabb,
    const float* __restrict__ points,
    const float* __restrict__ normals,
    float* __restrict__ out, int i)
{
    const float px = points[3 * i + 0], py = points[3 * i + 1], pz = points[3 * i + 2];
    const float nx = normals[3 * i + 0], ny = normals[3 * i + 1], nz = normals[3 * i + 2];
    int ix, iy, iz; float fx, fy, fz;
    grid_coords(aabb, px, py, pz, ix, iy, iz, fx, fy, fz);
    float sh[D2];
    sh_basis(nx, ny, nz, sh);
    const float wz0 = 1.0f - fz, wz1 = fz;
    float acc0 = 0.0f, acc1 = 0.0f, acc2 = 0.0f;
#pragma unroll
    for (int dx = 0; dx < 2; ++dx) {
        const float wx = dx ? fx : 1.0f - fx;
#pragma unroll
        for (int dy = 0; dy < 2; ++dy) {
            const float wxy = wx * (dy ? fy : 1.0f - fy);
            const int cell = (((ix + dx) * RES + (iy + dy)) * RES + iz) * CSTRIDE;
            const float4* __restrict__ cp = (const float4*)(coeff + cell);
            union { float4 q[24]; float v[96]; } u;
#pragma unroll
            for (int kk = 0; kk < 24; ++kk) u.q[kk] = cp[kk];
            float s00 = 0.f, s01 = 0.f, s02 = 0.f;
            float s10 = 0.f, s11 = 0.f, s12 = 0.f;
#pragma unroll
            for (int j = 0; j < D2; ++j) {
                const float s = sh[j];
                s00 = fmaf(s, u.v[3 * j + 0], s00);
                s01 = fmaf(s, u.v[3 * j + 1], s01);
                s02 = fmaf(s, u.v[3 * j + 2], s02);
                s10 = fmaf(s, u.v[48 + 3 * j + 0], s10);
                s11 = fmaf(s, u.v[48 + 3 * j + 1], s11);
                s12 = fmaf(s, u.v[48 + 3 * j + 2], s12);
            }
            const float w0 = wxy * wz0, w1 = wxy * wz1;
            acc0 = fmaf(w0, s00, fmaf(w1, s10, acc0));
            acc1 = fmaf(w0, s01, fmaf(w1, s11, acc1));
            acc2 = fmaf(w0, s02, fmaf(w1, s12, acc2));
        }
    }
    out[3 * i + 0] = fmaxf(acc0, 0.0f);
    out[3 * i + 1] = fmaxf(acc1, 0.0f);
    out[3 * i + 2] = fmaxf(acc2, 0.0f);
}

// ---------------- pass 0: zero counters ----------------
__global__ __launch_bounds__(256) void zero_kernel(uint4* __restrict__ p, int n16)
{
    for (int i = blockIdx.x * blockDim.x + threadIdx.x; i < n16; i += gridDim.x * blockDim.x)
        p[i] = make_uint4(0u, 0u, 0u, 0u);
}

// ---------------- pass 1: capacity-binned scatter, 64-B line-exclusive records ----
__global__ __launch_bounds__(256) void scatter_kernel(
    const float* __restrict__ aabb,
    const float* __restrict__ points,
    const float* __restrict__ normals,
    int* __restrict__ cnt_p,       // NBINS * REPL * CNT_PAD, pre-zeroed
    float4* __restrict__ slots4,   // NBINS * REPL * CAP slots x 64 B (4 float4)
    int* __restrict__ ovf_cnt,     // [0]=count, [1]=dropped flag; pre-zeroed
    int* __restrict__ ovf,         // OVF_CAP (indices)
    int n)
{
    const int i = blockIdx.x * blockDim.x + threadIdx.x;
    if (i >= n) return;
    const float px = points[3 * i + 0], py = points[3 * i + 1], pz = points[3 * i + 2];
    int ix, iy, iz; float fx, fy, fz;
    grid_coords(aabb, px, py, pz, ix, iy, iz, fx, fy, fz);
    const int bin = bin_of(ix, iy, iz);
    const int rep = (i >> 6) & (REPL - 1);   // wave-uniform replica choice
    const int g = bin * REPL + rep;
    const int pos = atomicAdd(&cnt_p[g * CNT_PAD], 1);
    if (pos < CAP) {
        const float nx = normals[3 * i + 0], ny = normals[3 * i + 1], nz = normals[3 * i + 2];
        const size_t rec = ((size_t)g * CAP + pos) * 4;  // private 64-B line
        slots4[rec + 0] = make_float4(px, py, pz, nx);
        slots4[rec + 1] = make_float4(ny, nz, __int_as_float(i), 0.0f);
        slots4[rec + 2] = make_float4(0.f, 0.f, 0.f, 0.f);  // full-line write: no RMW
        slots4[rec + 3] = make_float4(0.f, 0.f, 0.f, 0.f);
    } else {
        const int o = atomicAdd(&ovf_cnt[0], 1);
        if (o < OVF_CAP) ovf[o] = i;
        else ovf_cnt[1] = 1;  // adversarial input: signal full re-sweep
    }
}

// ---------------- staging helper (templated on thread count) ----------------
template <int NT>
__device__ __forceinline__ void stage_halo(
    float4* __restrict__ dst, const float4* __restrict__ coeff4,
    int x0, int y0, int z0, int t)
{
    constexpr int ITERS = (TOT_SRC_F4 + NT - 1) / NT;
#pragma unroll
    for (int k = 0; k < ITERS; ++k) {
        const int u = t + k * NT;
        if (u < TOT_SRC_F4) {
            int col = u / SRC_COL_F4;                // /108
            int rem = u - col * SRC_COL_F4;
            int cx = col / HY;                       // /9
            int cy = col - cx * HY;
            int cz = rem / CELL_F4;                  // /12
            int kk = rem - cz * CELL_F4;
            int xg = min(x0 + cx, RES - 1);
            int yg = min(y0 + cy, RES - 1);
            int zg = min(z0 + cz, RES - 1);
            dst[col * COL_F4 + rem] = coeff4[((xg * RES + yg) * RES + zg) * CELL_F4 + kk];
        }
    }
}

// ---------------- pass 2: persistent pipelined main ----------------
// 1 block/CU (157 KB LDS), 512 threads. Each block owns 32 consecutive bins.
// Waves 0-3 compute bin k from buf[k&1]; waves 4-7 stage bin k+1 into the other
// buffer (and 16 lanes of wave 7 prefetch bin k+1's counters).
__global__ __launch_bounds__(MAIN_THREADS, 1) void main_kernel(
    const float* __restrict__ coeff,
    const float* __restrict__ aabb,
    const float* __restrict__ points,
    const float* __restrict__ normals,
    const int* __restrict__ cnt_p,
    const float4* __restrict__ slots4,
    const int* __restrict__ ovf_cnt,
    const int* __restrict__ ovf,
    float* __restrict__ out,
    int n)
{
    extern __shared__ char smem[];
    float4* buf0 = (float4*)smem;
    float4* buf1 = buf0 + LDS_F4;
    __shared__ int s_cnt[2][REPL];
    __shared__ int s_pref[2][REPL + 1];

    const int tid = threadIdx.x;
    const int bin0 = blockIdx.x * BINS_PER_BLOCK;
    const float4* __restrict__ coeff4 = (const float4*)coeff;

    // ---- prologue: stage bin0 with all 512 threads; fetch its counters ----
    {
        const int bx = bin0 / (NBY * NBZ);
        const int by = (bin0 / NBZ) % NBY;
        const int bz = bin0 % NBZ;
        stage_halo<MAIN_THREADS>(buf0, coeff4, bx << 2, by << 3, bz << 3, tid);
        if (tid < REPL) s_cnt[0][tid] = min(cnt_p[(bin0 * REPL + tid) * CNT_PAD], CAP);
    }
    __syncthreads();
    if (tid == 0) {
        int run = 0;
        for (int r = 0; r < REPL; ++r) { s_pref[0][r] = run; run += s_cnt[0][r]; }
        s_pref[0][REPL] = run;
    }
    __syncthreads();

    for (int kb = 0; kb < BINS_PER_BLOCK; ++kb) {
        const int bin = bin0 + kb;
        const int cur = kb & 1;
        float4* bufc = cur ? buf1 : buf0;
        float4* bufn = cur ? buf0 : buf1;

        if (tid < 256) {
            // ---- compute bin k from bufc ----
            const int bx = bin / (NBY * NBZ);
            const int by = (bin / NBZ) % NBY;
            const int bz = bin % NBZ;
            const int x0 = bx << 2, y0 = by << 3, z0 = bz << 3;
            const int tot = s_pref[cur][REPL];
            for (int t = tid; t < tot; t += 256) {
                int r = 0;
                while (r < REPL - 1 && t >= s_pref[cur][r + 1]) ++r;
                const int k = t - s_pref[cur][r];
                const size_t rec = ((size_t)(bin * REPL + r) * CAP + k) * 4;
                const float4 lo = slots4[rec + 0];
                const float4 hi = slots4[rec + 1];
                eval_from_lds(bufc, aabb, lo.x, lo.y, lo.z, lo.w, hi.x, hi.y,
                              x0, y0, z0, __float_as_int(hi.z), out);
            }
        } else if (kb + 1 < BINS_PER_BLOCK) {
            // ---- stage bin k+1 into bufn ----
            const int nbin = bin + 1;
            const int nbx = nbin / (NBY * NBZ);
            const int nby = (nbin / NBZ) % NBY;
            const int nbz = nbin % NBZ;
            stage_halo<256>(bufn, coeff4, nbx << 2, nby << 3, nbz << 3, tid - 256);
            if (tid >= MAIN_THREADS - REPL) {
                const int r = tid - (MAIN_THREADS - REPL);
                s_cnt[1 - cur][r] = min(cnt_p[(nbin * REPL + r) * CNT_PAD], CAP);
            }
        }
        __syncthreads();
        if (tid == 0 && kb + 1 < BINS_PER_BLOCK) {
            int run = 0;
            for (int r = 0; r < REPL; ++r) { s_pref[1 - cur][r] = run; run += s_cnt[1 - cur][r]; }
            s_pref[1 - cur][REPL] = run;
        }
        __syncthreads();
    }

    // ---- overflow drain (block 0; expected 0 entries) ----
    if (blockIdx.x == 0) {
        const int m = min(ovf_cnt[0], OVF_CAP);
        for (int t = tid; t < m; t += MAIN_THREADS)
            compute_point_global(coeff, aabb, points, normals, out, ovf[t]);

        if (ovf_cnt[1]) {  // adversarial: re-derive placement per point
            for (int i = tid; i < n; i += MAIN_THREADS) {
                int ix, iy, iz; float fx, fy, fz;
                grid_coords(aabb, points[3 * i + 0], points[3 * i + 1], points[3 * i + 2],
                            ix, iy, iz, fx, fy, fz);
                const int g = bin_of(ix, iy, iz) * REPL + ((i >> 6) & (REPL - 1));
                const int c = min(cnt_p[g * CNT_PAD], CAP);
                bool placed = false;
                for (int k = 0; k < c && !placed; ++k)
                    placed = (__float_as_int(slots4[((size_t)g * CAP + k) * 4 + 1].z) == i);
                for (int k = 0; k < m && !placed; ++k) placed = (ovf[k] == i);
                if (!placed) compute_point_global(coeff, aabb, points, normals, out, i);
            }
        }
    }
}

// ---------------- fallback: direct, unsorted ----------------
__global__ __launch_bounds__(256) void direct_kernel(
    const float* __restrict__ coeff,
    const float* __restrict__ aabb,
    const float* __restrict__ points,
    const float* __restrict__ normals,
    float* __restrict__ out,
    int n)
{
    const int i = blockIdx.x * blockDim.x + threadIdx.x;
    if (i >= n) return;
    compute_point_global(coeff, aabb, points, normals, out, i);
}

extern "C" void kernel_launch(void* const* d_in, const int* in_sizes, int n_in,
                              void* d_out, int out_size, void* d_ws, size_t ws_size,
                              hipStream_t stream) {
    const float* coeff   = (const float*)d_in[0];
    const float* aabb    = (const float*)d_in[1];
    const float* points  = (const float*)d_in[2];
    const float* normals = (const float*)d_in[3];
    float* out = (float*)d_out;

    const int n = in_sizes[2] / 3;  // N_PTS
    const int nblk = (n + 255) / 256;
    char* ws = (char*)d_ws;

    const size_t cnt_bytes  = (size_t)NBINS * REPL * CNT_PAD * 4;   // 8 MB
    const size_t ovfc_bytes = 256;
    const size_t ovf_bytes  = (size_t)OVF_CAP * 4;                  // 512 KB
    const size_t slot_bytes = (size_t)NBINS * REPL * CAP * 64;      // 335 MB
    const size_t need = cnt_bytes + ovfc_bytes + ovf_bytes + slot_bytes; // ~344 MB

    if (ws_size < need) {
        hipLaunchKernelGGL(direct_kernel, dim3(nblk), dim3(256), 0, stream,
                           coeff, aabb, points, normals, out, n);
        return;
    }

    // layout: [cnt | ovf_cnt | ovf | slots]  (cnt+ovfc contiguous for one zero pass)
    int*    cnt_p   = (int*)(ws);
    int*    ovf_cnt = (int*)(ws + cnt_bytes);
    int*    ovf     = (int*)(ws + cnt_bytes + ovfc_bytes);
    float4* slots4  = (float4*)(ws + cnt_bytes + ovfc_bytes + ovf_bytes);

    const int zero16 = (int)((cnt_bytes + ovfc_bytes) / 16);
    hipLaunchKernelGGL(zero_kernel, dim3(2048), dim3(256), 0, stream,
                       (uint4*)ws, zero16);

    hipLaunchKernelGGL(scatter_kernel, dim3(nblk), dim3(256), 0, stream,
                       aabb, points, normals, cnt_p, slots4, ovf_cnt, ovf, n);

    hipLaunchKernelGGL(main_kernel, dim3(MAIN_GRID), dim3(MAIN_THREADS),
                       2 * LDS_F4 * sizeof(float4), stream,
                       coeff, aabb, points, normals, cnt_p, slots4, ovf_cnt, ovf, out, n);
}

// Round 6
// 787.775 us; speedup vs baseline: 1.0301x; 1.0301x over previous
//
#include <hip/hip_runtime.h>

// IrradianceVolumes: out[i,c] = relu( sum_j sh_j(normal_i) * trilerp(coeff[...,j,c], point_i) )
// coeff: [128,128,128,16,3] f32 (403 MB), points/normals: [2M,3] f32, out: [2M,3] f32.
//
// Round 10:
//  - Cross-round subtraction (poison fill = constant 248us): scatter ~290us in rounds
//    7/8/9 regardless of payload (4/32/64 B) or replica count (4/16). Traffic is only
//    ~30us -> the cost is the 2M device-scope RETURNING atomics (executed at the
//    coherence point past the non-coherent per-XCD L2s; ~7 atomics/cy device-wide)
//    plus cross-XCD line sharing on slot writes.
//  - Fix: chunk-local LDS binning. 512 scatter blocks; block c owns points
//    [c*4096,(c+1)*4096), bins them via a PRIVATE 32-KB LDS histogram (LDS atomics,
//    CU-local), writes 32-B records to slots[bin][c][pos] - each 256-B group (CAPC=8)
//    is written by exactly ONE block (no shared lines), counts exported as
//    cnt8[c][bin] (4 MB, coalesced). ZERO device atomics on the hot path; no global
//    counter zeroing needed. lambda=0.5/group -> expected overflow ~0.01 points.
//  - main: REVERTED to round-8 proven structure (per-bin blocks, 256 thr, single
//    78,480-B z-column-padded halo buffer, 2 blocks/CU). Adds a ~30-instr shfl/LDS
//    prefix-scan over the 512 chunk counts + 9-step binary search per point.
//  - Round-9 pipeline (4-wave compute) and REPL16/64-B scatter: REVERTED (regressed).

constexpr int RES = 128;
constexpr int D2 = 16;
constexpr int CSTRIDE = D2 * 3;       // 48 floats per cell
constexpr int CELL_F4 = CSTRIDE / 4;  // 12 float4 per cell

// bins: x split by 4 (shift 2), y/z by 8 (shift 3)
constexpr int NBX = 32, NBY = 16, NBZ = 16;
constexpr int NBINS = NBX * NBY * NBZ;     // 8192
constexpr int HX = 5, HY = 9, HZ = 9;      // halo cells per axis

// LDS halo layout: [col = cx*HY+cy][z-column of 9 cells, padded +1 f4]
constexpr int SRC_COL_F4 = HZ * CELL_F4;        // 108 f4 real data per column
constexpr int COL_F4 = SRC_COL_F4 + 1;          // 109 -> bank-group spread (5 coprime 8)
constexpr int NCOL = HX * HY;                   // 45 columns
constexpr int TOT_SRC_F4 = NCOL * SRC_COL_F4;   // 4860 f4 staged from HBM per bin
constexpr int LDS_F4 = NCOL * COL_F4;           // 4905 f4 = 78,480 B
constexpr int MAIN_THREADS = 256;
constexpr int LOAD_ITERS = (TOT_SRC_F4 + MAIN_THREADS - 1) / MAIN_THREADS; // 19

constexpr int MAXCHUNK = 512;    // max point chunks (scatter blocks)
constexpr int CHUNK_PTS0 = 4096; // nominal points per chunk (lambda = 0.5 per group)
constexpr int CAPC = 8;          // records per (bin,chunk) group -> 256 B, line-exclusive
constexpr int OVF_CAP = 131072;  // overflow list capacity (512 KB)

__device__ __forceinline__ void grid_coords(const float* aabb, float px, float py, float pz,
                                            int& ix, int& iy, int& iz,
                                            float& fx, float& fy, float& fz)
{
    const float a0 = aabb[0], a1 = aabb[1], a2 = aabb[2];
    const float b0 = aabb[3], b1 = aabb[4], b2 = aabb[5];
    float gx = (px - a0) / (b0 - a0) * (float)(RES - 1);
    float gy = (py - a1) / (b1 - a1) * (float)(RES - 1);
    float gz = (pz - a2) / (b2 - a2) * (float)(RES - 1);
    gx = fminf(fmaxf(gx, 0.0f), (float)(RES - 1));
    gy = fminf(fmaxf(gy, 0.0f), (float)(RES - 1));
    gz = fminf(fmaxf(gz, 0.0f), (float)(RES - 1));
    ix = min((int)floorf(gx), RES - 2);
    iy = min((int)floorf(gy), RES - 2);
    iz = min((int)floorf(gz), RES - 2);
    fx = gx - (float)ix;
    fy = gy - (float)iy;
    fz = gz - (float)iz;
}

__device__ __forceinline__ int bin_of(int ix, int iy, int iz)
{
    return (((ix >> 2) * NBY) + (iy >> 3)) * NBZ + (iz >> 3);
}

__device__ __forceinline__ void sh_basis(float nx, float ny, float nz, float* sh)
{
    const float xx = nx * nx, yy = ny * ny, zz = nz * nz;
    const float xy = nx * ny, yz = ny * nz, xz = nx * nz;
    sh[0]  = 0.28209479177387814f;
    sh[1]  = -0.4886025119029199f * ny;
    sh[2]  = 0.4886025119029199f * nz;
    sh[3]  = -0.4886025119029199f * nx;
    sh[4]  = 1.0925484305920792f * xy;
    sh[5]  = -1.0925484305920792f * yz;
    sh[6]  = 0.31539156525252005f * (2.0f * zz - xx - yy);
    sh[7]  = -1.0925484305920792f * xz;
    sh[8]  = 0.5462742152960396f * (xx - yy);
    sh[9]  = -0.5900435899266435f * ny * (3.0f * xx - yy);
    sh[10] = 2.890611442640554f * xy * nz;
    sh[11] = -0.4570457994644658f * ny * (4.0f * zz - xx - yy);
    sh[12] = 0.3731763325901154f * nz * (2.0f * zz - 3.0f * xx - 3.0f * yy);
    sh[13] = -0.4570457994644658f * nx * (4.0f * zz - xx - yy);
    sh[14] = 1.445305721320277f * nz * (xx - yy);
    sh[15] = -0.5900435899266435f * nx * (xx - 3.0f * yy);
}

// Shared inner math: given point/normal + LDS halo buffer, accumulate and store.
__device__ __forceinline__ void eval_from_lds(
    const float4* __restrict__ lds4, const float* __restrict__ aabb,
    float px, float py, float pz, float nx, float ny, float nz,
    int x0, int y0, int z0, int i, float* __restrict__ out)
{
    int ix, iy, iz; float fx, fy, fz;
    grid_coords(aabb, px, py, pz, ix, iy, iz, fx, fy, fz);
    const int lx = ix - x0, ly = iy - y0, lz = iz - z0;

    float sh[D2];
    sh_basis(nx, ny, nz, sh);

    const float wz0 = 1.0f - fz, wz1 = fz;
    float acc0 = 0.0f, acc1 = 0.0f, acc2 = 0.0f;

#pragma unroll
    for (int dx = 0; dx < 2; ++dx) {
        const float wx = dx ? fx : 1.0f - fx;
#pragma unroll
        for (int dy = 0; dy < 2; ++dy) {
            const float wxy = wx * (dy ? fy : 1.0f - fy);
            // contiguous 24 f4 within one padded z-column (covers lz, lz+1)
            const int lbase = ((lx + dx) * HY + (ly + dy)) * COL_F4 + lz * CELL_F4;
            union { float4 q[24]; float v[96]; } u;
#pragma unroll
            for (int kk = 0; kk < 24; ++kk) u.q[kk] = lds4[lbase + kk];

            float s00 = 0.f, s01 = 0.f, s02 = 0.f;
            float s10 = 0.f, s11 = 0.f, s12 = 0.f;
#pragma unroll
            for (int j = 0; j < D2; ++j) {
                const float s = sh[j];
                s00 = fmaf(s, u.v[3 * j + 0], s00);
                s01 = fmaf(s, u.v[3 * j + 1], s01);
                s02 = fmaf(s, u.v[3 * j + 2], s02);
                s10 = fmaf(s, u.v[48 + 3 * j + 0], s10);
                s11 = fmaf(s, u.v[48 + 3 * j + 1], s11);
                s12 = fmaf(s, u.v[48 + 3 * j + 2], s12);
            }
            const float w0 = wxy * wz0, w1 = wxy * wz1;
            acc0 = fmaf(w0, s00, fmaf(w1, s10, acc0));
            acc1 = fmaf(w0, s01, fmaf(w1, s11, acc1));
            acc2 = fmaf(w0, s02, fmaf(w1, s12, acc2));
        }
    }

    out[3 * i + 0] = fmaxf(acc0, 0.0f);
    out[3 * i + 1] = fmaxf(acc1, 0.0f);
    out[3 * i + 2] = fmaxf(acc2, 0.0f);
}

// Fully-direct per-point evaluation from global memory (fallback / overflow path).
__device__ void compute_point_global(
    const float* __restrict__ coeff,
    const float* __restrict__ aabb,
    const float* __restrict__ points,
    const float* __restrict__ normals,
    float* __restrict__ out, int i)
{
    const float px = points[3 * i + 0], py = points[3 * i + 1], pz = points[3 * i + 2];
    const float nx = normals[3 * i + 0], ny = normals[3 * i + 1], nz = normals[3 * i + 2];
    int ix, iy, iz; float fx, fy, fz;
    grid_coords(aabb, px, py, pz, ix, iy, iz, fx, fy, fz);
    float sh[D2];
    sh_basis(nx, ny, nz, sh);
    const float wz0 = 1.0f - fz, wz1 = fz;
    float acc0 = 0.0f, acc1 = 0.0f, acc2 = 0.0f;
#pragma unroll
    for (int dx = 0; dx < 2; ++dx) {
        const float wx = dx ? fx : 1.0f - fx;
#pragma unroll
        for (int dy = 0; dy < 2; ++dy) {
            const float wxy = wx * (dy ? fy : 1.0f - fy);
            const int cell = (((ix + dx) * RES + (iy + dy)) * RES + iz) * CSTRIDE;
            const float4* __restrict__ cp = (const float4*)(coeff + cell);
            union { float4 q[24]; float v[96]; } u;
#pragma unroll
            for (int kk = 0; kk < 24; ++kk) u.q[kk] = cp[kk];
            float s00 = 0.f, s01 = 0.f, s02 = 0.f;
            float s10 = 0.f, s11 = 0.f, s12 = 0.f;
#pragma unroll
            for (int j = 0; j < D2; ++j) {
                const float s = sh[j];
                s00 = fmaf(s, u.v[3 * j + 0], s00);
                s01 = fmaf(s, u.v[3 * j + 1], s01);
                s02 = fmaf(s, u.v[3 * j + 2], s02);
                s10 = fmaf(s, u.v[48 + 3 * j + 0], s10);
                s11 = fmaf(s, u.v[48 + 3 * j + 1], s11);
                s12 = fmaf(s, u.v[48 + 3 * j + 2], s12);
            }
            const float w0 = wxy * wz0, w1 = wxy * wz1;
            acc0 = fmaf(w0, s00, fmaf(w1, s10, acc0));
            acc1 = fmaf(w0, s01, fmaf(w1, s11, acc1));
            acc2 = fmaf(w0, s02, fmaf(w1, s12, acc2));
        }
    }
    out[3 * i + 0] = fmaxf(acc0, 0.0f);
    out[3 * i + 1] = fmaxf(acc1, 0.0f);
    out[3 * i + 2] = fmaxf(acc2, 0.0f);
}

// ---------------- pass 1: chunk-local LDS binning scatter (NO device atomics) -------
// Block c owns points [c*chunk_pts, ...); private LDS histogram gives exact in-chunk
// positions; records land in line-exclusive 256-B groups slots[bin][c][0..CAPC).
__global__ __launch_bounds__(256) void scatter_kernel(
    const float* __restrict__ aabb,
    const float* __restrict__ points,
    const float* __restrict__ normals,
    float4* __restrict__ slots4,          // [NBINS][nchunk][CAPC] x 32 B
    unsigned char* __restrict__ cnt8,     // [nchunk][NBINS]
    int* __restrict__ ovf_cnt,            // [0]=count, [1]=dropped flag; pre-zeroed
    int* __restrict__ ovf,                // OVF_CAP (indices)
    int n, int nchunk, int chunk_pts)
{
    __shared__ int scnt[NBINS];           // 32 KB
    const int c = blockIdx.x;
    const int tid = threadIdx.x;

    for (int j = tid; j < NBINS; j += 256) scnt[j] = 0;
    __syncthreads();

    const int base = c * chunk_pts;
    const int limit = min(chunk_pts, n - base);
    for (int k = tid; k < limit; k += 256) {
        const int i = base + k;
        const float px = points[3 * i + 0], py = points[3 * i + 1], pz = points[3 * i + 2];
        int ix, iy, iz; float fx, fy, fz;
        grid_coords(aabb, px, py, pz, ix, iy, iz, fx, fy, fz);
        const int bin = bin_of(ix, iy, iz);
        const int pos = atomicAdd(&scnt[bin], 1);       // LDS atomic: CU-local
        if (pos < CAPC) {
            const float nx = normals[3 * i + 0], ny = normals[3 * i + 1], nz = normals[3 * i + 2];
            const size_t rec = ((size_t)bin * nchunk + c) * CAPC + pos;
            slots4[rec * 2 + 0] = make_float4(px, py, pz, nx);
            slots4[rec * 2 + 1] = make_float4(ny, nz, __int_as_float(i), 0.0f);
        } else {
            const int o = atomicAdd(&ovf_cnt[0], 1);    // rare (~0.01 expected)
            if (o < OVF_CAP) ovf[o] = i;
            else ovf_cnt[1] = 1;                        // adversarial: full re-sweep
        }
    }
    __syncthreads();

    for (int j = tid; j < NBINS; j += 256)
        cnt8[(size_t)c * NBINS + j] = (unsigned char)min(scnt[j], CAPC);
}

// ---------------- pass 2: one block per bin, LDS-staged gather ----------------
__global__ __launch_bounds__(MAIN_THREADS) void main_kernel(
    const float* __restrict__ coeff,
    const float* __restrict__ aabb,
    const float* __restrict__ points,
    const float* __restrict__ normals,
    const unsigned char* __restrict__ cnt8,
    const float4* __restrict__ slots4,
    const int* __restrict__ ovf_cnt,
    const int* __restrict__ ovf,
    float* __restrict__ out,
    int n, int nchunk, int chunk_pts)
{
    extern __shared__ char smem[];
    float4* lds4 = (float4*)smem;
    __shared__ int pref[MAXCHUNK + 1];
    __shared__ int wsum[4];

    const int bin = blockIdx.x;
    const int tid = threadIdx.x;
    const bool ovfb = (bin == 0);

    // ---- per-bin chunk counts -> exclusive prefix (shfl + LDS scan) ----
    const int c0i = 2 * tid, c1i = 2 * tid + 1;
    int cc0 = (c0i < nchunk) ? (int)cnt8[(size_t)c0i * NBINS + bin] : 0;
    int cc1 = (c1i < nchunk) ? (int)cnt8[(size_t)c1i * NBINS + bin] : 0;
    int s = cc0 + cc1;
    const int lane = tid & 63, wv = tid >> 6;
    for (int d = 1; d < 64; d <<= 1) {
        int v = __shfl_up(s, d, 64);
        if (lane >= d) s += v;
    }
    if (lane == 63) wsum[wv] = s;
    __syncthreads();
    int woff = 0;
    for (int w = 0; w < wv; ++w) woff += wsum[w];
    const int incl = s + woff;
    pref[c0i] = incl - cc1 - cc0;
    pref[c1i] = incl - cc1;
    if (tid == 255) pref[MAXCHUNK] = incl;
    __syncthreads();
    const int tot = pref[MAXCHUNK];

    if (tot == 0 && !ovfb) return;

    if (tot > 0) {
        const int bx = bin / (NBY * NBZ);
        const int by = (bin / NBZ) % NBY;
        const int bz = bin % NBZ;
        const int x0 = bx << 2, y0 = by << 3, z0 = bz << 3;
        const float4* __restrict__ coeff4 = (const float4*)coeff;

        // ---- stage 5x9x9-cell halo into LDS (z-column-padded layout) ----
#pragma unroll
        for (int k = 0; k < LOAD_ITERS; ++k) {
            const int u = tid + k * MAIN_THREADS;
            if (u < TOT_SRC_F4) {
                int col = u / SRC_COL_F4;                // /108
                int rem = u - col * SRC_COL_F4;
                int cx = col / HY;                       // /9
                int cy = col - cx * HY;
                int cz = rem / CELL_F4;                  // /12
                int kk = rem - cz * CELL_F4;
                int xg = min(x0 + cx, RES - 1);
                int yg = min(y0 + cy, RES - 1);
                int zg = min(z0 + cz, RES - 1);
                lds4[col * COL_F4 + rem] = coeff4[((xg * RES + yg) * RES + zg) * CELL_F4 + kk];
            }
        }
        __syncthreads();

        // ---- compute this bin's points ----
        const int hi_end = min(nchunk, MAXCHUNK);
        for (int t = tid; t < tot; t += MAIN_THREADS) {
            // largest ch with pref[ch] <= t  (pref[0]=0, pref[nchunk]=tot)
            int a = 0, b = hi_end;
            while (b - a > 1) {
                const int m = (a + b) >> 1;
                if (pref[m] <= t) a = m; else b = m;
            }
            const int pos = t - pref[a];
            const size_t rec = ((size_t)bin * nchunk + a) * CAPC + pos;
            const float4 lo4 = slots4[rec * 2 + 0];
            const float4 hi4 = slots4[rec * 2 + 1];
            eval_from_lds(lds4, aabb, lo4.x, lo4.y, lo4.z, lo4.w, hi4.x, hi4.y,
                          x0, y0, z0, __float_as_int(hi4.z), out);
        }
    }

    // ---- overflow drain (block 0; expected ~0 entries) ----
    if (ovfb) {
        const int m = min(ovf_cnt[0], OVF_CAP);
        for (int t = tid; t < m; t += MAIN_THREADS)
            compute_point_global(coeff, aabb, points, normals, out, ovf[t]);

        if (ovf_cnt[1]) {  // adversarial: re-derive placement per point
            for (int i = tid; i < n; i += MAIN_THREADS) {
                int ix, iy, iz; float fx, fy, fz;
                grid_coords(aabb, points[3 * i + 0], points[3 * i + 1], points[3 * i + 2],
                            ix, iy, iz, fx, fy, fz);
                const int b2 = bin_of(ix, iy, iz);
                const int ch = i / chunk_pts;
                const int c = (int)cnt8[(size_t)ch * NBINS + b2];
                bool placed = false;
                for (int k = 0; k < c && !placed; ++k) {
                    const size_t rec = ((size_t)b2 * nchunk + ch) * CAPC + k;
                    placed = (__float_as_int(slots4[rec * 2 + 1].z) == i);
                }
                for (int k = 0; k < m && !placed; ++k) placed = (ovf[k] == i);
                if (!placed) compute_point_global(coeff, aabb, points, normals, out, i);
            }
        }
    }
}

// ---------------- fallback: direct, unsorted ----------------
__global__ __launch_bounds__(256) void direct_kernel(
    const float* __restrict__ coeff,
    const float* __restrict__ aabb,
    const float* __restrict__ points,
    const float* __restrict__ normals,
    float* __restrict__ out,
    int n)
{
    const int i = blockIdx.x * blockDim.x + threadIdx.x;
    if (i >= n) return;
    compute_point_global(coeff, aabb, points, normals, out, i);
}

extern "C" void kernel_launch(void* const* d_in, const int* in_sizes, int n_in,
                              void* d_out, int out_size, void* d_ws, size_t ws_size,
                              hipStream_t stream) {
    const float* coeff   = (const float*)d_in[0];
    const float* aabb    = (const float*)d_in[1];
    const float* points  = (const float*)d_in[2];
    const float* normals = (const float*)d_in[3];
    float* out = (float*)d_out;

    const int n = in_sizes[2] / 3;  // N_PTS
    char* ws = (char*)d_ws;

    // chunking: nominal 4096 pts/chunk, capped at MAXCHUNK chunks
    int nchunk = (n + CHUNK_PTS0 - 1) / CHUNK_PTS0;
    if (nchunk > MAXCHUNK) nchunk = MAXCHUNK;
    if (nchunk < 1) nchunk = 1;
    const int chunk_pts = (n + nchunk - 1) / nchunk;

    const size_t ovfc_bytes = 256;
    const size_t ovf_bytes  = (size_t)OVF_CAP * 4;                        // 512 KB
    const size_t cnt_bytes  = ((size_t)nchunk * NBINS + 255) & ~(size_t)255; // <=4 MB
    const size_t slot_bytes = (size_t)NBINS * nchunk * CAPC * 32;         // <=1.074 GB
    const size_t need = ovfc_bytes + ovf_bytes + cnt_bytes + slot_bytes;

    if (ws_size < need) {
        const int nblk = (n + 255) / 256;
        hipLaunchKernelGGL(direct_kernel, dim3(nblk), dim3(256), 0, stream,
                           coeff, aabb, points, normals, out, n);
        return;
    }

    int*           ovf_cnt = (int*)(ws);
    int*           ovf     = (int*)(ws + ovfc_bytes);
    unsigned char* cnt8    = (unsigned char*)(ws + ovfc_bytes + ovf_bytes);
    float4*        slots4  = (float4*)(ws + ovfc_bytes + ovf_bytes + cnt_bytes);

    hipMemsetAsync(ovf_cnt, 0, ovfc_bytes, stream);   // 256 B only

    hipLaunchKernelGGL(scatter_kernel, dim3(nchunk), dim3(256), 0, stream,
                       aabb, points, normals, slots4, cnt8, ovf_cnt, ovf,
                       n, nchunk, chunk_pts);

    hipLaunchKernelGGL(main_kernel, dim3(NBINS), dim3(MAIN_THREADS),
                       LDS_F4 * sizeof(float4), stream,
                       coeff, aabb, points, normals, cnt8, slots4, ovf_cnt, ovf, out,
                       n, nchunk, chunk_pts);
}